// Round 1
// 743.476 us; speedup vs baseline: 1.1689x; 1.1689x over previous
//
#include <hip/hip_runtime.h>
#include <hip/hip_bf16.h>
#include <stdint.h>
#include <math.h>

#define DM 1024
#define DH 2048
#define NB 4
#define SL 4096
#define MT (NB*SL)   // 16384 rows
#define LC 256       // scan chunk length
#define NC (SL/LC)   // 16 chunks per channel

typedef __bf16 bf16;
typedef __attribute__((ext_vector_type(8))) __bf16 bf16x8;
typedef __attribute__((ext_vector_type(4))) __bf16 bf16x4;
typedef __attribute__((ext_vector_type(4))) float f32x4;

// ===========================================================================
// fp32 -> bf16 sanitizing convert (NaN -> 0, clamp +-65504). Vectorized x4.
// All sizes in this problem are divisible by 4.
// ===========================================================================
__global__ void cvt_kernel(const float* __restrict__ in, bf16* __restrict__ out, int n) {
  const int n4 = n >> 2;
  for (int i = blockIdx.x * 256 + threadIdx.x; i < n4; i += gridDim.x * 256) {
    f32x4 v = *(const f32x4*)(in + 4 * (size_t)i);
    bf16x4 o;
#pragma unroll
    for (int j = 0; j < 4; ++j) {
      float x = v[j];
      x = (x == x) ? fminf(fmaxf(x, -65504.f), 65504.f) : 0.f;
      o[j] = (bf16)x;
    }
    *(bf16x4*)(out + 4 * (size_t)i) = o;
  }
}

// ===========================================================================
// GEMM: out[M,N] = A[M,K] @ W[N,K]^T (+bias), fused epilogues.
// Round-9 change: LDS-restage epilogue. Round-8 PMC showed the GEMMs are
// epilogue-bound, not K-loop-bound: MfmaUtil 17.8% with VALUBusy 80.7%,
// WRITE_SIZE 103MB for a 64MB bf16 output and FETCH_SIZE 104MB vs ~36MB
// compulsory — the per-element 2-byte stores (64 global_store_short/thread)
// force read-modify-write of every output line, and MODE 3/5 used precise
// libm expf/log1pf. Now: each wave restages its 64x64 fp32 accumulator
// quadrant through a private LDS slot (stride-68 rows => <=2-way bank
// aliasing, free per m136) and emits bf16x8 / float4 stores (16-32B/lane,
// 128B contiguous per 8-lane row group). extra[]/bias reads vectorized.
// __expf/__logf replace libm calls.
// K-loop unchanged (reg-prefetch pipeline, XOR-swizzled LDS, 0 conflicts).
// 128x128 tile, BK=64, 4 waves (2x2 of 64x64), mfma_f32_16x16x32_bf16.
// MODE 0: out_bf16 = acc (+bias)
// MODE 1: out_f32  = acc + bias
// MODE 2: out_bf16 = acc + bias + extra_f32[off]
// MODE 3: out_bf16 = extra_bf16[off] * silu(acc)            (z-gate)
// MODE 4: out_f32  = acc + extra_bf16[off]                  (residual, final)
// MODE 5: out_bf16 = softplus(acc + bias)                   (delta)
// MODE 6: out_bf16 = extra_bf16[off] * (acc + bias)         (nla = delta*A_t)
// ===========================================================================
template<int MODE, bool HAS_BIAS, int N, int K>
__global__ __launch_bounds__(256, 3)
void gemm_bt(const bf16* __restrict__ A, const bf16* __restrict__ W,
             const float* __restrict__ bias, const void* __restrict__ extra,
             void* __restrict__ outp) {
  // LDS pool: K-loop uses [0,32768) as lds_a/lds_b; epilogue reuses the whole
  // pool as 4 per-wave fp32 slots of 32x68 floats (8704B each, 34816 total).
  __shared__ __align__(16) char pool[34816];
  bf16* lds_a = (bf16*)pool;
  bf16* lds_b = (bf16*)(pool + 16384);

  const int tid  = threadIdx.x;
  const int wave = tid >> 6;
  const int lane = tid & 63;
  const int wm = wave >> 1, wn = wave & 1;

  // XCD-aware swizzle: consecutive blockIdx round-robin XCDs (id&7); give
  // each XCD a contiguous bm range with bn fastest -> same-bm group shares
  // its XCD's L2 copy of the A-tiles. Bijective for gridDim.y % 8 == 0.
  constexpr int NBN = N / 128;
  const int nbm8 = (int)(gridDim.y >> 3);
  const int id   = (int)(blockIdx.y * NBN + blockIdx.x);
  const int xcd  = id & 7;
  const unsigned jj = (unsigned)id >> 3;
  const int bm   = xcd * nbm8 + (int)(jj / (unsigned)NBN);
  const int bn   = (int)(jj & (NBN - 1));

  const int r_in = lane >> 3;             // row within 8-row chunk
  const int kc_l = (lane & 7) ^ r_in;     // swizzle: this lane stages k-chunk c^r
  const size_t arow0 = (size_t)bm * 128;
  const size_t brow0 = (size_t)bn * 128;

  f32x4 acc[4][4];
#pragma unroll
  for (int i = 0; i < 4; ++i)
#pragma unroll
    for (int j = 0; j < 4; ++j) acc[i][j] = {0.f, 0.f, 0.f, 0.f};

  const int mrow = lane & 15;
  const int kg   = lane >> 4;

  // Per-lane staging pointers (K compile-time => strength-reduced bumps).
  const bf16* pa[4];
  const bf16* pb[4];
#pragma unroll
  for (int iss = 0; iss < 4; ++iss) {
    const int chunk = iss * 4 + wave;
    const int row   = chunk * 8 + r_in;
    pa[iss] = A + (arow0 + row) * (size_t)K + kc_l * 8;
    pb[iss] = W + (brow0 + row) * (size_t)K + kc_l * 8;
  }

  // Prologue: tile 0 -> VGPRs.
  bf16x8 va[4], vb[4];
#pragma unroll
  for (int iss = 0; iss < 4; ++iss) {
    va[iss] = *(const bf16x8*)pa[iss]; pa[iss] += 64;
    vb[iss] = *(const bf16x8*)pb[iss]; pb[iss] += 64;
  }

#pragma unroll 1
  for (int k0 = 0; k0 < K; k0 += 64) {
    __syncthreads();  // previous tile's LDS readers done before overwrite
#pragma unroll
    for (int iss = 0; iss < 4; ++iss) {
      const int chunk = iss * 4 + wave;
      *(bf16x8*)&lds_a[chunk * 512 + lane * 8] = va[iss];   // waits own vmcnt only
      *(bf16x8*)&lds_b[chunk * 512 + lane * 8] = vb[iss];
    }
    __syncthreads();  // LDS tile valid
    if (k0 + 64 < K) {      // prefetch tile k+1; lands during MFMA below
#pragma unroll
      for (int iss = 0; iss < 4; ++iss) {
        va[iss] = *(const bf16x8*)pa[iss]; pa[iss] += 64;
        vb[iss] = *(const bf16x8*)pb[iss]; pb[iss] += 64;
      }
    }
#pragma unroll
    for (int ks = 0; ks < 2; ++ks) {
      bf16x8 af[4], bfr[4];
#pragma unroll
      for (int t = 0; t < 4; ++t) {
        const int ra = wm * 64 + t * 16 + mrow;
        const int sa = ra * 8 + ((ks * 4 + kg) ^ (ra & 7));
        af[t] = *(const bf16x8*)&lds_a[sa * 8];
        const int rb = wn * 64 + t * 16 + mrow;
        const int sb = rb * 8 + ((ks * 4 + kg) ^ (rb & 7));
        bfr[t] = *(const bf16x8*)&lds_b[sb * 8];
      }
#pragma unroll
      for (int i = 0; i < 4; ++i)
#pragma unroll
        for (int j = 0; j < 4; ++j)
          acc[i][j] = __builtin_amdgcn_mfma_f32_16x16x32_bf16(af[i], bfr[j], acc[i][j], 0, 0, 0);
    }
  }

  // =========================================================================
  // Epilogue: restage through LDS for coalesced 16B-per-lane stores.
  // C/D fragment layout: col = lane&15 (mrow), row = kg*4 + r within each
  // 16x16 tile; wave quadrant is 64x64 at (wm*64, wn*64). Two passes of 32
  // rows (i in {0,1} then {2,3}); each wave uses a private 32x68 fp32 slot
  // (stride 68 => write groups kg{0,2}/kg{1,3} alias 2-way = free).
  // Read-back: lane -> (row = lane>>3, colchunk = (lane&7)*8); 8 rows x 64
  // cols per round, 4 rounds per pass. Global stores are 16B/lane, 128B
  // contiguous per 8-lane row group => no partial-line RMW.
  // =========================================================================
  __syncthreads();                         // all waves done with K-loop LDS
  float* eps = (float*)pool + wave * 2176; // 32*68 floats per wave
  const int rr  = lane >> 3;
  const int cc  = (lane & 7) * 8;
  const int gcol0 = bn * 128 + wn * 64 + cc;
  f32x4 bv0 = {0.f, 0.f, 0.f, 0.f}, bv1 = {0.f, 0.f, 0.f, 0.f};
  if constexpr (HAS_BIAS) {
    bv0 = *(const f32x4*)(bias + gcol0);
    bv1 = *(const f32x4*)(bias + gcol0 + 4);
  }

#pragma unroll
  for (int p = 0; p < 2; ++p) {
    // -- write phase: this wave's rows [p*32, p*32+32) into its slot --
#pragma unroll
    for (int ii = 0; ii < 2; ++ii) {
      const int i = p * 2 + ii;
#pragma unroll
      for (int j = 0; j < 4; ++j) {
#pragma unroll
        for (int r = 0; r < 4; ++r) {
          const int lr = ii * 16 + kg * 4 + r;      // 0..31
          eps[lr * 68 + j * 16 + mrow] = acc[i][j][r];
        }
      }
    }
    // -- read phase (same-wave DS ops execute in order; slot is private) --
#pragma unroll
    for (int rnd = 0; rnd < 4; ++rnd) {
      const int lr   = rnd * 8 + rr;                // 0..31
      const int grow = bm * 128 + wm * 64 + p * 32 + lr;
      f32x4 v0 = *(const f32x4*)&eps[lr * 68 + cc];
      f32x4 v1 = *(const f32x4*)&eps[lr * 68 + cc + 4];
      const size_t off = (size_t)grow * N + gcol0;
      float vv[8];
#pragma unroll
      for (int k = 0; k < 4; ++k) { vv[k] = v0[k] + bv0[k]; vv[4 + k] = v1[k] + bv1[k]; }

      float res[8];
      if constexpr (MODE == 0 || MODE == 1) {
#pragma unroll
        for (int k = 0; k < 8; ++k) res[k] = vv[k];
      } else if constexpr (MODE == 2) {
        f32x4 e0 = *(const f32x4*)((const float*)extra + off);
        f32x4 e1 = *(const f32x4*)((const float*)extra + off + 4);
#pragma unroll
        for (int k = 0; k < 4; ++k) { res[k] = vv[k] + e0[k]; res[4 + k] = vv[4 + k] + e1[k]; }
      } else if constexpr (MODE == 3) {
        bf16x8 g = *(const bf16x8*)((const bf16*)extra + off);
#pragma unroll
        for (int k = 0; k < 8; ++k) {
          const float v = vv[k];
          res[k] = (float)g[k] * (v / (1.f + __expf(-v)));
        }
      } else if constexpr (MODE == 4) {
        bf16x8 e = *(const bf16x8*)((const bf16*)extra + off);
#pragma unroll
        for (int k = 0; k < 8; ++k) res[k] = vv[k] + (float)e[k];
      } else if constexpr (MODE == 5) {
#pragma unroll
        for (int k = 0; k < 8; ++k) {
          const float v = vv[k];
          res[k] = (v > 15.f) ? v : __logf(1.f + __expf(v));
        }
      } else {  // MODE 6
        bf16x8 d = *(const bf16x8*)((const bf16*)extra + off);
#pragma unroll
        for (int k = 0; k < 8; ++k) res[k] = (float)d[k] * vv[k];
      }

      if constexpr (MODE == 1 || MODE == 4) {
        f32x4 o0, o1;
#pragma unroll
        for (int k = 0; k < 4; ++k) { o0[k] = res[k]; o1[k] = res[4 + k]; }
        *(f32x4*)((float*)outp + off)     = o0;
        *(f32x4*)((float*)outp + off + 4) = o1;
      } else {
        bf16x8 o;
#pragma unroll
        for (int k = 0; k < 8; ++k) o[k] = (bf16)res[k];
        *(bf16x8*)((bf16*)outp + off) = o;
      }
    }
  }
}

// ===========================================================================
// depthwise conv1d(k=3, pad=1 along L, per-batch) + bias + silu. 8 d's/thread.
// ===========================================================================
__global__ void conv_silu_kernel(const bf16* __restrict__ t1, const float* __restrict__ cw,
                                 const float* __restrict__ cb, bf16* __restrict__ xc) {
  const int gid  = blockIdx.x * 256 + threadIdx.x;   // MT*DM/8 threads
  const int dgrp = gid & (DM / 8 - 1);
  const int bl   = gid >> 7;
  const int l    = bl & (SL - 1);
  const int d0   = dgrp * 8;
  const bf16* p  = t1 + (size_t)bl * DM + d0;
  bf16x8 cc = *(const bf16x8*)p;
  bf16x8 lf, rt;
#pragma unroll
  for (int j = 0; j < 8; ++j) { lf[j] = (bf16)0.f; rt[j] = (bf16)0.f; }
  if (l > 0)      lf = *(const bf16x8*)(p - DM);
  if (l < SL - 1) rt = *(const bf16x8*)(p + DM);
  bf16x8 o;
#pragma unroll
  for (int j = 0; j < 8; ++j) {
    const int d = d0 + j;
    float y = cw[d * 3 + 0] * (float)lf[j] + cw[d * 3 + 1] * (float)cc[j]
            + cw[d * 3 + 2] * (float)rt[j] + cb[d];
    y = y / (1.f + __expf(-y));
    o[j] = (bf16)y;
  }
  *(bf16x8*)(xc + (size_t)bl * DM + d0) = o;
}

// ===========================================================================
// Parallel scan over L, 3 phases, chunked (LC=256, NC=16).
// h_l = sum_{i<=l} Bx_i * exp(-sum_{j<=i} nla_j).
// ===========================================================================
__global__ void scan_phase1(bf16* nla_sl, const bf16* __restrict__ bx,
                            float* __restrict__ Lp_tot, float* __restrict__ T_tot) {
  const int g  = blockIdx.x * 256 + threadIdx.x;   // 131072 threads
  const int ch = g & (DH - 1);
  const int rc = g >> 11;          // 0..63
  const int b  = rc & (NB - 1);
  const int c  = rc >> 2;          // 0..15
  const int bc = b * DH + ch;
  size_t off = ((size_t)(b * SL + c * LC)) * DH + ch;
  float lp = 0.f, S = 0.f;
#pragma unroll 8
  for (int l = 0; l < LC; ++l, off += DH) {
    const float a = (float)nla_sl[off];
    const float x = (float)bx[off];
    lp += a;
    const float e = __expf(-fminf(fmaxf(lp, -80.f), 80.f));
    S = fmaf(x, e, S);
    nla_sl[off] = (bf16)S;
  }
  Lp_tot[c * (NB * DH) + bc] = lp;
  T_tot [c * (NB * DH) + bc] = S;
}

__global__ void scan_phase2(const float* __restrict__ Lp_tot, const float* __restrict__ T_tot,
                            float* __restrict__ lpoff, float* __restrict__ Soff) {
  const int bc = blockIdx.x * 256 + threadIdx.x;   // 0..8191
  float lp = 0.f, S = 0.f;
#pragma unroll
  for (int c = 0; c < NC; ++c) {
    lpoff[c * (NB * DH) + bc] = lp;
    Soff [c * (NB * DH) + bc] = S;
    const float e = __expf(-fminf(fmaxf(lp, -80.f), 80.f));
    S  = fmaf(e, T_tot[c * (NB * DH) + bc], S);
    lp += Lp_tot[c * (NB * DH) + bc];
  }
}

__global__ void scan_phase3(const bf16* __restrict__ S_local, bf16* __restrict__ h,
                            const float* __restrict__ lpoff, const float* __restrict__ Soff) {
  const int g  = blockIdx.x * 256 + threadIdx.x;
  const int ch = g & (DH - 1);
  const int rc = g >> 11;
  const int b  = rc & (NB - 1);
  const int c  = rc >> 2;
  const int bc = b * DH + ch;
  const float lo = lpoff[c * (NB * DH) + bc];
  const float so = Soff [c * (NB * DH) + bc];
  const float es = __expf(-fminf(fmaxf(lo, -80.f), 80.f));
  size_t off = ((size_t)(b * SL + c * LC)) * DH + ch;
#pragma unroll 8
  for (int l = 0; l < LC; ++l, off += DH) {
    h[off] = (bf16)fmaf(es, (float)S_local[off], so);
  }
}

// ===========================================================================
// Workspace (max live 186 MB <= proven-safe 192 MB), offsets in MB:
//  [  0.. 24): bf16 weights (persistent)
//  [ 24.. 56): xc -> ssm
//  [ 56..120): t1/xbf -> dlo -> bxh (Bx, then h) ; z
//  [120..184): nla -> S_local (in-place) -> dtmp (fp32)
//  [184..186): scan totals
// ===========================================================================
extern "C" void kernel_launch(void* const* d_in, const int* in_sizes, int n_in,
                              void* d_out, int out_size, void* d_ws, size_t ws_size,
                              hipStream_t stream) {
  const float* x    = (const float*)d_in[0];
  const float* w1   = (const float*)d_in[1];
  const float* w2   = (const float*)d_in[2];
  const float* w3   = (const float*)d_in[3];
  const float* cw   = (const float*)d_in[4];
  const float* cb   = (const float*)d_in[5];
  const float* A_w  = (const float*)d_in[6];
  const float* A_b  = (const float*)d_in[7];
  const float* B_w  = (const float*)d_in[8];
  const float* B_b  = (const float*)d_in[9];
  const float* C_w  = (const float*)d_in[10];
  const float* C_b  = (const float*)d_in[11];
  const float* D_w  = (const float*)d_in[12];
  const float* D_b  = (const float*)d_in[13];
  const float* dl_w = (const float*)d_in[14];
  const float* dl_b = (const float*)d_in[15];

  const size_t MB = 1048576u;
  char* ws = (char*)d_ws;
  bf16* w1b  = (bf16*)(ws + 0*MB);
  bf16* w2b  = (bf16*)(ws + 2*MB);
  bf16* w3b  = (bf16*)(ws + 4*MB);
  bf16* Dwb  = (bf16*)(ws + 6*MB);
  bf16* Awb  = (bf16*)(ws + 8*MB);
  bf16* Bwb  = (bf16*)(ws + 12*MB);
  bf16* dlwb = (bf16*)(ws + 16*MB);
  bf16* Cwb  = (bf16*)(ws + 20*MB);
  bf16* xc   = (bf16*)(ws + 24*MB);
  bf16* ssm  = xc;
  bf16* t1   = (bf16*)(ws + 56*MB);
  bf16* z    = t1;
  bf16* xbf  = (bf16*)(ws + 88*MB);
  bf16* dlo  = (bf16*)(ws + 56*MB);   // 64 MB region
  bf16* bxh  = dlo;                    // Bx, then h (phase3 writes)
  bf16* nla  = (bf16*)(ws + 120*MB);  // 64 MB; S_local in-place; then dtmp
  float* dtmp = (float*)nla;
  float* Lp_tot = (float*)(ws + 184*MB);
  float* T_tot  = (float*)(ws + 184*MB + 524288u);
  float* lpoff  = (float*)(ws + 185*MB);
  float* Soff   = (float*)(ws + 185*MB + 524288u);
  float* outp = (float*)d_out;

  dim3 blk(256);
  dim3 g1(DM / 128, MT / 128);   // N=1024
  dim3 g2(DH / 128, MT / 128);   // N=2048

  // --- convert inputs to bf16 (sanitizing) ---
  cvt_kernel<<<4096, blk, 0, stream>>>(x,    xbf,  MT*DM);
  cvt_kernel<<<512,  blk, 0, stream>>>(w1,   w1b,  DM*DM);
  cvt_kernel<<<512,  blk, 0, stream>>>(w2,   w2b,  DM*DM);
  cvt_kernel<<<512,  blk, 0, stream>>>(w3,   w3b,  DM*DM);
  cvt_kernel<<<512,  blk, 0, stream>>>(D_w,  Dwb,  DM*DM);
  cvt_kernel<<<1024, blk, 0, stream>>>(A_w,  Awb,  DH*DM);
  cvt_kernel<<<1024, blk, 0, stream>>>(B_w,  Bwb,  DH*DM);
  cvt_kernel<<<1024, blk, 0, stream>>>(dl_w, dlwb, DH*DM);
  cvt_kernel<<<1024, blk, 0, stream>>>(C_w,  Cwb,  DM*DH);

  // --- pipeline ---
  gemm_bt<0,false,DM,DM><<<g1, blk, 0, stream>>>(xbf, w1b,  nullptr, nullptr, t1);
  conv_silu_kernel<<<MT * DM / 8 / 256, blk, 0, stream>>>(t1, cw, cb, xc);
  gemm_bt<5,true ,DH,DM><<<g2, blk, 0, stream>>>(xc,  dlwb, dl_b,    nullptr, dlo);
  gemm_bt<6,true ,DH,DM><<<g2, blk, 0, stream>>>(xc,  Awb,  A_b,     dlo,     nla);
  gemm_bt<0,true ,DH,DM><<<g2, blk, 0, stream>>>(xc,  Bwb,  B_b,     nullptr, bxh);
  scan_phase1<<<MT * NC * DH / SL / 256, blk, 0, stream>>>(nla, bxh, Lp_tot, T_tot);
  scan_phase2<<<NB * DH / 256, blk, 0, stream>>>(Lp_tot, T_tot, lpoff, Soff);
  scan_phase3<<<MT * NC * DH / SL / 256, blk, 0, stream>>>(nla, bxh, lpoff, Soff);
  gemm_bt<1,true ,DM,DM><<<g1, blk, 0, stream>>>(xc,  Dwb,  D_b,     nullptr, dtmp);
  gemm_bt<2,true ,DM,DH><<<g1, blk, 0, stream>>>(bxh, Cwb,  C_b,     dtmp,    ssm);
  gemm_bt<3,false,DM,DM><<<g1, blk, 0, stream>>>(ssm, w2b,  nullptr, ssm,     z);
  gemm_bt<4,false,DM,DM><<<g1, blk, 0, stream>>>(z,   w3b,  nullptr, ssm,     outp);
}

// Round 2
// 661.126 us; speedup vs baseline: 1.3145x; 1.1246x over previous
//
#include <hip/hip_runtime.h>
#include <hip/hip_bf16.h>
#include <stdint.h>
#include <math.h>

#define DM 1024
#define DH 2048
#define NB 4
#define SL 4096
#define MT (NB*SL)   // 16384 rows
#define LC 256       // scan chunk length
#define NC (SL/LC)   // 16 chunks per channel

typedef __bf16 bf16;
typedef __attribute__((ext_vector_type(8))) __bf16 bf16x8;
typedef __attribute__((ext_vector_type(4))) __bf16 bf16x4;
typedef __attribute__((ext_vector_type(4))) float f32x4;

// ===========================================================================
// fp32 -> bf16 sanitizing convert (NaN -> 0, clamp +-65504). Vectorized x4.
// ===========================================================================
__global__ void cvt_kernel(const float* __restrict__ in, bf16* __restrict__ out, int n) {
  const int n4 = n >> 2;
  for (int i = blockIdx.x * 256 + threadIdx.x; i < n4; i += gridDim.x * 256) {
    f32x4 v = *(const f32x4*)(in + 4 * (size_t)i);
    bf16x4 o;
#pragma unroll
    for (int j = 0; j < 4; ++j) {
      float x = v[j];
      x = (x == x) ? fminf(fmaxf(x, -65504.f), 65504.f) : 0.f;
      o[j] = (bf16)x;
    }
    *(bf16x4*)(out + 4 * (size_t)i) = o;
  }
}

// ===========================================================================
// Round-2 changes (round-1 PMC: MfmaUtil 32.8, VALUBusy 35.4, WRITE exactly
// 64MB -> epilogue fixed; GEMM K-loop now the limiter at ~767 TF effective):
//  1. Staging switched reg-prefetch -> global_load_lds width=16 (m97-proven
//     874-912 TF at identical 128x128/BK=64/2-barrier structure). Our
//     source-side XOR swizzle (kc_l) + linear LDS dest at lane*16 is exactly
//     the pre-swizzled-global pattern gload_lds requires; frag-read swizzle
//     unchanged. Frees the va/vb prefetch VGPRs and 8 ds_writes/K-step.
//  2. MODE5+MODE6 fused into gemm_dual: nla = softplus(dl.x+b1)*(A.x+b2)
//     with dual accumulators sharing the A-tile. Kills dlo (64MB write +
//     64MB read) + one 32MB A pass + one launch.
//  3. MODE1+MODE2 fused as concatenated-K pass: ssm = C.h + D.x + bC + bD.
//     Kills dtmp (64MB fp32 write + 64MB read) + one launch.
// Epilogue (LDS restage, coalesced bf16x8/f32x4 stores) kept from round 1.
// MODE 0: out_bf16 = acc (+bias1 (+bias2 if K2))
// MODE 1: out_f32  = acc + extra_bf16[off]          (final residual)
// MODE 2: out_bf16 = extra_bf16[off] * silu(acc)    (z-gate)
// ===========================================================================

__device__ __forceinline__ void g2lds(const bf16* g, bf16* l) {
  __builtin_amdgcn_global_load_lds((const __attribute__((address_space(1))) void*)g,
                                   (__attribute__((address_space(3))) void*)l,
                                   16, 0, 0);
}

// One K-pass: stages [128 rows x 64 k] of A and W via global_load_lds and
// accumulates into acc. 2 barriers per K-step (m97 structure).
template<int KK>
__device__ __forceinline__ void gemm_pass(const bf16* __restrict__ Abase,
                                          const bf16* __restrict__ Wbase,
                                          bf16* lds_a, bf16* lds_b,
                                          f32x4 (&acc)[4][4],
                                          int wave, int lane,
                                          size_t arow0, size_t brow0) {
  const int wm = wave >> 1, wn = wave & 1;
  const int r_in = lane >> 3;
  const int kc_l = (lane & 7) ^ r_in;     // pre-swizzled global k-chunk
  const int mrow = lane & 15;
  const int kg   = lane >> 4;

  const bf16* pa[4];
  const bf16* pb[4];
#pragma unroll
  for (int iss = 0; iss < 4; ++iss) {
    const int row = (iss * 4 + wave) * 8 + r_in;
    pa[iss] = Abase + (arow0 + row) * (size_t)KK + kc_l * 8;
    pb[iss] = Wbase + (brow0 + row) * (size_t)KK + kc_l * 8;
  }

#pragma unroll 1
  for (int k0 = 0; k0 < KK; k0 += 64) {
    __syncthreads();                      // prev tile's readers done
#pragma unroll
    for (int iss = 0; iss < 4; ++iss) {
      const int chunk = iss * 4 + wave;   // wave-uniform LDS base; lane*16 implicit
      g2lds(pa[iss], &lds_a[chunk * 512]); pa[iss] += 64;
      g2lds(pb[iss], &lds_b[chunk * 512]); pb[iss] += 64;
    }
    __syncthreads();                      // vmcnt(0) drain => tile valid
#pragma unroll
    for (int ks = 0; ks < 2; ++ks) {
      bf16x8 af[4], bfr[4];
#pragma unroll
      for (int t = 0; t < 4; ++t) {
        const int ra = wm * 64 + t * 16 + mrow;
        const int sa = ra * 8 + ((ks * 4 + kg) ^ (ra & 7));
        af[t] = *(const bf16x8*)&lds_a[sa * 8];
        const int rb = wn * 64 + t * 16 + mrow;
        const int sb = rb * 8 + ((ks * 4 + kg) ^ (rb & 7));
        bfr[t] = *(const bf16x8*)&lds_b[sb * 8];
      }
#pragma unroll
      for (int i = 0; i < 4; ++i)
#pragma unroll
        for (int j = 0; j < 4; ++j)
          acc[i][j] = __builtin_amdgcn_mfma_f32_16x16x32_bf16(af[i], bfr[j], acc[i][j], 0, 0, 0);
    }
  }
}

template<int MODE, bool HAS_BIAS, int N, int K1, int K2>
__global__ __launch_bounds__(256, 3)
void gemm_bt(const bf16* __restrict__ A1, const bf16* __restrict__ W1,
             const float* __restrict__ bias1,
             const bf16* __restrict__ A2, const bf16* __restrict__ W2,
             const float* __restrict__ bias2,
             const void* __restrict__ extra, void* __restrict__ outp) {
  // K-loop uses [0,32768); epilogue reuses pool as 4 per-wave 32x68 f32 slots.
  __shared__ __align__(16) char pool[34816];
  bf16* lds_a = (bf16*)pool;
  bf16* lds_b = (bf16*)(pool + 16384);

  const int tid  = threadIdx.x;
  const int wave = tid >> 6;
  const int lane = tid & 63;
  const int wm = wave >> 1, wn = wave & 1;

  // XCD-aware swizzle (bijective: gridDim.y % 8 == 0).
  constexpr int NBN = N / 128;
  const int nbm8 = (int)(gridDim.y >> 3);
  const int id   = (int)(blockIdx.y * NBN + blockIdx.x);
  const int xcd  = id & 7;
  const unsigned jj = (unsigned)id >> 3;
  const int bm   = xcd * nbm8 + (int)(jj / (unsigned)NBN);
  const int bn   = (int)(jj & (NBN - 1));
  const size_t arow0 = (size_t)bm * 128;
  const size_t brow0 = (size_t)bn * 128;

  f32x4 acc[4][4];
#pragma unroll
  for (int i = 0; i < 4; ++i)
#pragma unroll
    for (int j = 0; j < 4; ++j) acc[i][j] = {0.f, 0.f, 0.f, 0.f};

  gemm_pass<K1>(A1, W1, lds_a, lds_b, acc, wave, lane, arow0, brow0);
  if constexpr (K2 > 0)
    gemm_pass<K2>(A2, W2, lds_a, lds_b, acc, wave, lane, arow0, brow0);

  const int mrow = lane & 15;
  const int kg   = lane >> 4;

  // Epilogue: LDS restage -> coalesced stores (see round-1 notes).
  __syncthreads();
  float* eps = (float*)pool + wave * 2176; // 32*68 floats per wave
  const int rr  = lane >> 3;
  const int cc  = (lane & 7) * 8;
  const int gcol0 = bn * 128 + wn * 64 + cc;
  f32x4 bv0 = {0.f, 0.f, 0.f, 0.f}, bv1 = {0.f, 0.f, 0.f, 0.f};
  if constexpr (HAS_BIAS) {
    bv0 = *(const f32x4*)(bias1 + gcol0);
    bv1 = *(const f32x4*)(bias1 + gcol0 + 4);
  }
  if constexpr (K2 > 0) {
    bv0 += *(const f32x4*)(bias2 + gcol0);
    bv1 += *(const f32x4*)(bias2 + gcol0 + 4);
  }

#pragma unroll
  for (int p = 0; p < 2; ++p) {
#pragma unroll
    for (int ii = 0; ii < 2; ++ii) {
      const int i = p * 2 + ii;
#pragma unroll
      for (int j = 0; j < 4; ++j)
#pragma unroll
        for (int r = 0; r < 4; ++r)
          eps[(ii * 16 + kg * 4 + r) * 68 + j * 16 + mrow] = acc[i][j][r];
    }
#pragma unroll
    for (int rnd = 0; rnd < 4; ++rnd) {
      const int lr   = rnd * 8 + rr;
      const int grow = bm * 128 + wm * 64 + p * 32 + lr;
      f32x4 v0 = *(const f32x4*)&eps[lr * 68 + cc];
      f32x4 v1 = *(const f32x4*)&eps[lr * 68 + cc + 4];
      const size_t off = (size_t)grow * N + gcol0;
      float vv[8];
#pragma unroll
      for (int k = 0; k < 4; ++k) { vv[k] = v0[k] + bv0[k]; vv[4 + k] = v1[k] + bv1[k]; }

      float res[8];
      if constexpr (MODE == 0) {
#pragma unroll
        for (int k = 0; k < 8; ++k) res[k] = vv[k];
      } else if constexpr (MODE == 1) {
        bf16x8 e = *(const bf16x8*)((const bf16*)extra + off);
#pragma unroll
        for (int k = 0; k < 8; ++k) res[k] = vv[k] + (float)e[k];
      } else {  // MODE 2
        bf16x8 g = *(const bf16x8*)((const bf16*)extra + off);
#pragma unroll
        for (int k = 0; k < 8; ++k) {
          const float v = vv[k];
          res[k] = (float)g[k] * (v / (1.f + __expf(-v)));
        }
      }

      if constexpr (MODE == 1) {
        f32x4 o0, o1;
#pragma unroll
        for (int k = 0; k < 4; ++k) { o0[k] = res[k]; o1[k] = res[4 + k]; }
        *(f32x4*)((float*)outp + off)     = o0;
        *(f32x4*)((float*)outp + off + 4) = o1;
      } else {
        bf16x8 o;
#pragma unroll
        for (int k = 0; k < 8; ++k) o[k] = (bf16)res[k];
        *(bf16x8*)((bf16*)outp + off) = o;
      }
    }
  }
}

// ===========================================================================
// Dual GEMM: nla = softplus(A.dlw^T + b1) * (A.Aw^T + b2). Shares the A-tile
// across two accumulators; W1/W2 each staged. N=2048, K=1024.
// ===========================================================================
template<int N, int K>
__global__ __launch_bounds__(256, 2)
void gemm_dual(const bf16* __restrict__ A, const bf16* __restrict__ W1,
               const bf16* __restrict__ W2, const float* __restrict__ b1,
               const float* __restrict__ b2, bf16* __restrict__ outp) {
  // K-loop: 3 tiles (A, W1, W2) = 49152 B. Epilogue: 4 waves x 2 slots x 8704 B.
  __shared__ __align__(16) char pool[69632];
  bf16* lds_a  = (bf16*)pool;
  bf16* lds_b1 = (bf16*)(pool + 16384);
  bf16* lds_b2 = (bf16*)(pool + 32768);

  const int tid  = threadIdx.x;
  const int wave = tid >> 6;
  const int lane = tid & 63;
  const int wm = wave >> 1, wn = wave & 1;

  constexpr int NBN = N / 128;
  const int nbm8 = (int)(gridDim.y >> 3);
  const int id   = (int)(blockIdx.y * NBN + blockIdx.x);
  const int xcd  = id & 7;
  const unsigned jj = (unsigned)id >> 3;
  const int bm   = xcd * nbm8 + (int)(jj / (unsigned)NBN);
  const int bn   = (int)(jj & (NBN - 1));
  const size_t arow0 = (size_t)bm * 128;
  const size_t brow0 = (size_t)bn * 128;

  const int r_in = lane >> 3;
  const int kc_l = (lane & 7) ^ r_in;
  const int mrow = lane & 15;
  const int kg   = lane >> 4;

  f32x4 acc1[4][4], acc2[4][4];
#pragma unroll
  for (int i = 0; i < 4; ++i)
#pragma unroll
    for (int j = 0; j < 4; ++j) { acc1[i][j] = {0.f,0.f,0.f,0.f}; acc2[i][j] = {0.f,0.f,0.f,0.f}; }

  const bf16* pa[4]; const bf16* pb1[4]; const bf16* pb2[4];
#pragma unroll
  for (int iss = 0; iss < 4; ++iss) {
    const int row = (iss * 4 + wave) * 8 + r_in;
    pa[iss]  = A  + (arow0 + row) * (size_t)K + kc_l * 8;
    pb1[iss] = W1 + (brow0 + row) * (size_t)K + kc_l * 8;
    pb2[iss] = W2 + (brow0 + row) * (size_t)K + kc_l * 8;
  }

#pragma unroll 1
  for (int k0 = 0; k0 < K; k0 += 64) {
    __syncthreads();
#pragma unroll
    for (int iss = 0; iss < 4; ++iss) {
      const int chunk = iss * 4 + wave;
      g2lds(pa[iss],  &lds_a [chunk * 512]); pa[iss]  += 64;
      g2lds(pb1[iss], &lds_b1[chunk * 512]); pb1[iss] += 64;
      g2lds(pb2[iss], &lds_b2[chunk * 512]); pb2[iss] += 64;
    }
    __syncthreads();
#pragma unroll
    for (int ks = 0; ks < 2; ++ks) {
      bf16x8 af[4], b1f[4], b2f[4];
#pragma unroll
      for (int t = 0; t < 4; ++t) {
        const int ra = wm * 64 + t * 16 + mrow;
        const int sa = ra * 8 + ((ks * 4 + kg) ^ (ra & 7));
        af[t] = *(const bf16x8*)&lds_a[sa * 8];
        const int rb = wn * 64 + t * 16 + mrow;
        const int sb = rb * 8 + ((ks * 4 + kg) ^ (rb & 7));
        b1f[t] = *(const bf16x8*)&lds_b1[sb * 8];
        b2f[t] = *(const bf16x8*)&lds_b2[sb * 8];
      }
#pragma unroll
      for (int i = 0; i < 4; ++i)
#pragma unroll
        for (int j = 0; j < 4; ++j) {
          acc1[i][j] = __builtin_amdgcn_mfma_f32_16x16x32_bf16(af[i], b1f[j], acc1[i][j], 0, 0, 0);
          acc2[i][j] = __builtin_amdgcn_mfma_f32_16x16x32_bf16(af[i], b2f[j], acc2[i][j], 0, 0, 0);
        }
    }
  }

  // Epilogue: two restage slots per wave (acc1, acc2), fused softplus*linear.
  __syncthreads();
  float* eps1 = (float*)pool + wave * 4352;
  float* eps2 = eps1 + 2176;
  const int rr  = lane >> 3;
  const int cc  = (lane & 7) * 8;
  const int gcol0 = bn * 128 + wn * 64 + cc;
  f32x4 b1v0 = *(const f32x4*)(b1 + gcol0);
  f32x4 b1v1 = *(const f32x4*)(b1 + gcol0 + 4);
  f32x4 b2v0 = *(const f32x4*)(b2 + gcol0);
  f32x4 b2v1 = *(const f32x4*)(b2 + gcol0 + 4);

#pragma unroll
  for (int p = 0; p < 2; ++p) {
#pragma unroll
    for (int ii = 0; ii < 2; ++ii) {
      const int i = p * 2 + ii;
#pragma unroll
      for (int j = 0; j < 4; ++j)
#pragma unroll
        for (int r = 0; r < 4; ++r) {
          const int lr = ii * 16 + kg * 4 + r;
          eps1[lr * 68 + j * 16 + mrow] = acc1[i][j][r];
          eps2[lr * 68 + j * 16 + mrow] = acc2[i][j][r];
        }
    }
#pragma unroll
    for (int rnd = 0; rnd < 4; ++rnd) {
      const int lr   = rnd * 8 + rr;
      const int grow = bm * 128 + wm * 64 + p * 32 + lr;
      f32x4 u0 = *(const f32x4*)&eps1[lr * 68 + cc];
      f32x4 u1 = *(const f32x4*)&eps1[lr * 68 + cc + 4];
      f32x4 w0 = *(const f32x4*)&eps2[lr * 68 + cc];
      f32x4 w1v = *(const f32x4*)&eps2[lr * 68 + cc + 4];
      const size_t off = (size_t)grow * N + gcol0;
      bf16x8 o;
#pragma unroll
      for (int k = 0; k < 8; ++k) {
        const float dv = (k < 4 ? u0[k] + b1v0[k] : u1[k - 4] + b1v1[k - 4]);
        const float av = (k < 4 ? w0[k] + b2v0[k] : w1v[k - 4] + b2v1[k - 4]);
        const float sp = (dv > 15.f) ? dv : __logf(1.f + __expf(dv));
        o[k] = (bf16)(sp * av);
      }
      *(bf16x8*)(outp + off) = o;
    }
  }
}

// ===========================================================================
// depthwise conv1d(k=3, pad=1 along L, per-batch) + bias + silu. 8 d's/thread.
// ===========================================================================
__global__ void conv_silu_kernel(const bf16* __restrict__ t1, const float* __restrict__ cw,
                                 const float* __restrict__ cb, bf16* __restrict__ xc) {
  const int gid  = blockIdx.x * 256 + threadIdx.x;
  const int dgrp = gid & (DM / 8 - 1);
  const int bl   = gid >> 7;
  const int l    = bl & (SL - 1);
  const int d0   = dgrp * 8;
  const bf16* p  = t1 + (size_t)bl * DM + d0;
  bf16x8 cc = *(const bf16x8*)p;
  bf16x8 lf, rt;
#pragma unroll
  for (int j = 0; j < 8; ++j) { lf[j] = (bf16)0.f; rt[j] = (bf16)0.f; }
  if (l > 0)      lf = *(const bf16x8*)(p - DM);
  if (l < SL - 1) rt = *(const bf16x8*)(p + DM);
  bf16x8 o;
#pragma unroll
  for (int j = 0; j < 8; ++j) {
    const int d = d0 + j;
    float y = cw[d * 3 + 0] * (float)lf[j] + cw[d * 3 + 1] * (float)cc[j]
            + cw[d * 3 + 2] * (float)rt[j] + cb[d];
    y = y / (1.f + __expf(-y));
    o[j] = (bf16)y;
  }
  *(bf16x8*)(xc + (size_t)bl * DM + d0) = o;
}

// ===========================================================================
// Parallel scan over L, 3 phases, chunked (LC=256, NC=16).
// ===========================================================================
__global__ void scan_phase1(bf16* nla_sl, const bf16* __restrict__ bx,
                            float* __restrict__ Lp_tot, float* __restrict__ T_tot) {
  const int g  = blockIdx.x * 256 + threadIdx.x;
  const int ch = g & (DH - 1);
  const int rc = g >> 11;
  const int b  = rc & (NB - 1);
  const int c  = rc >> 2;
  const int bc = b * DH + ch;
  size_t off = ((size_t)(b * SL + c * LC)) * DH + ch;
  float lp = 0.f, S = 0.f;
#pragma unroll 8
  for (int l = 0; l < LC; ++l, off += DH) {
    const float a = (float)nla_sl[off];
    const float x = (float)bx[off];
    lp += a;
    const float e = __expf(-fminf(fmaxf(lp, -80.f), 80.f));
    S = fmaf(x, e, S);
    nla_sl[off] = (bf16)S;
  }
  Lp_tot[c * (NB * DH) + bc] = lp;
  T_tot [c * (NB * DH) + bc] = S;
}

__global__ void scan_phase2(const float* __restrict__ Lp_tot, const float* __restrict__ T_tot,
                            float* __restrict__ lpoff, float* __restrict__ Soff) {
  const int bc = blockIdx.x * 256 + threadIdx.x;
  float lp = 0.f, S = 0.f;
#pragma unroll
  for (int c = 0; c < NC; ++c) {
    lpoff[c * (NB * DH) + bc] = lp;
    Soff [c * (NB * DH) + bc] = S;
    const float e = __expf(-fminf(fmaxf(lp, -80.f), 80.f));
    S  = fmaf(e, T_tot[c * (NB * DH) + bc], S);
    lp += Lp_tot[c * (NB * DH) + bc];
  }
}

__global__ void scan_phase3(const bf16* __restrict__ S_local, bf16* __restrict__ h,
                            const float* __restrict__ lpoff, const float* __restrict__ Soff) {
  const int g  = blockIdx.x * 256 + threadIdx.x;
  const int ch = g & (DH - 1);
  const int rc = g >> 11;
  const int b  = rc & (NB - 1);
  const int c  = rc >> 2;
  const int bc = b * DH + ch;
  const float lo = lpoff[c * (NB * DH) + bc];
  const float so = Soff [c * (NB * DH) + bc];
  const float es = __expf(-fminf(fmaxf(lo, -80.f), 80.f));
  size_t off = ((size_t)(b * SL + c * LC)) * DH + ch;
#pragma unroll 8
  for (int l = 0; l < LC; ++l, off += DH) {
    h[off] = (bf16)fmaf(es, (float)S_local[off], so);
  }
}

// ===========================================================================
// Workspace (max live 186 MB), offsets in MB:
//  [  0.. 24): bf16 weights (persistent)
//  [ 24.. 56): xc
//  [ 56..120): t1 [56,88) / xbf [88,120) -> bxh (Bx, then h) ; z [56,88)
//  [120..184): nla (scan in-place) -> ssm [120,152)
//  [184..186): scan totals
// ===========================================================================
extern "C" void kernel_launch(void* const* d_in, const int* in_sizes, int n_in,
                              void* d_out, int out_size, void* d_ws, size_t ws_size,
                              hipStream_t stream) {
  const float* x    = (const float*)d_in[0];
  const float* w1   = (const float*)d_in[1];
  const float* w2   = (const float*)d_in[2];
  const float* w3   = (const float*)d_in[3];
  const float* cw   = (const float*)d_in[4];
  const float* cb   = (const float*)d_in[5];
  const float* A_w  = (const float*)d_in[6];
  const float* A_b  = (const float*)d_in[7];
  const float* B_w  = (const float*)d_in[8];
  const float* B_b  = (const float*)d_in[9];
  const float* C_w  = (const float*)d_in[10];
  const float* C_b  = (const float*)d_in[11];
  const float* D_w  = (const float*)d_in[12];
  const float* D_b  = (const float*)d_in[13];
  const float* dl_w = (const float*)d_in[14];
  const float* dl_b = (const float*)d_in[15];

  const size_t MB = 1048576u;
  char* ws = (char*)d_ws;
  bf16* w1b  = (bf16*)(ws + 0*MB);
  bf16* w2b  = (bf16*)(ws + 2*MB);
  bf16* w3b  = (bf16*)(ws + 4*MB);
  bf16* Dwb  = (bf16*)(ws + 6*MB);
  bf16* Awb  = (bf16*)(ws + 8*MB);
  bf16* Bwb  = (bf16*)(ws + 12*MB);
  bf16* dlwb = (bf16*)(ws + 16*MB);
  bf16* Cwb  = (bf16*)(ws + 20*MB);
  bf16* xc   = (bf16*)(ws + 24*MB);
  bf16* t1   = (bf16*)(ws + 56*MB);
  bf16* z    = t1;
  bf16* xbf  = (bf16*)(ws + 88*MB);
  bf16* bxh  = (bf16*)(ws + 56*MB);   // 64 MB: Bx, then h (phase3 in-place)
  bf16* nla  = (bf16*)(ws + 120*MB);  // 64 MB; S_local in-place
  bf16* ssm  = (bf16*)(ws + 120*MB);  // 32 MB, after nla dies (post-scan3)
  float* Lp_tot = (float*)(ws + 184*MB);
  float* T_tot  = (float*)(ws + 184*MB + 524288u);
  float* lpoff  = (float*)(ws + 185*MB);
  float* Soff   = (float*)(ws + 185*MB + 524288u);
  float* outp = (float*)d_out;

  dim3 blk(256);
  dim3 g1(DM / 128, MT / 128);   // N=1024
  dim3 g2(DH / 128, MT / 128);   // N=2048

  // --- convert inputs to bf16 (sanitizing) ---
  cvt_kernel<<<4096, blk, 0, stream>>>(x,    xbf,  MT*DM);
  cvt_kernel<<<512,  blk, 0, stream>>>(w1,   w1b,  DM*DM);
  cvt_kernel<<<512,  blk, 0, stream>>>(w2,   w2b,  DM*DM);
  cvt_kernel<<<512,  blk, 0, stream>>>(w3,   w3b,  DM*DM);
  cvt_kernel<<<512,  blk, 0, stream>>>(D_w,  Dwb,  DM*DM);
  cvt_kernel<<<1024, blk, 0, stream>>>(A_w,  Awb,  DH*DM);
  cvt_kernel<<<1024, blk, 0, stream>>>(B_w,  Bwb,  DH*DM);
  cvt_kernel<<<1024, blk, 0, stream>>>(dl_w, dlwb, DH*DM);
  cvt_kernel<<<1024, blk, 0, stream>>>(C_w,  Cwb,  DM*DH);

  // --- pipeline ---
  gemm_bt<0,false,DM,DM,0><<<g1, blk, 0, stream>>>(xbf, w1b, nullptr,
      nullptr, nullptr, nullptr, nullptr, t1);
  conv_silu_kernel<<<MT * DM / 8 / 256, blk, 0, stream>>>(t1, cw, cb, xc);
  gemm_dual<DH,DM><<<g2, blk, 0, stream>>>(xc, dlwb, Awb, dl_b, A_b, nla);
  gemm_bt<0,true ,DH,DM,0><<<g2, blk, 0, stream>>>(xc, Bwb, B_b,
      nullptr, nullptr, nullptr, nullptr, bxh);
  scan_phase1<<<MT * NC * DH / SL / 256, blk, 0, stream>>>(nla, bxh, Lp_tot, T_tot);
  scan_phase2<<<NB * DH / 256, blk, 0, stream>>>(Lp_tot, T_tot, lpoff, Soff);
  scan_phase3<<<MT * NC * DH / SL / 256, blk, 0, stream>>>(nla, bxh, lpoff, Soff);
  // ssm = C.h + D.x + C_b + D_b  (concatenated-K fused pass)
  gemm_bt<0,true ,DM,DH,DM><<<g1, blk, 0, stream>>>(bxh, Cwb, C_b,
      xc, Dwb, D_b, nullptr, ssm);
  gemm_bt<2,false,DM,DM,0><<<g1, blk, 0, stream>>>(ssm, w2b, nullptr,
      nullptr, nullptr, nullptr, ssm, z);
  gemm_bt<1,false,DM,DM,0><<<g1, blk, 0, stream>>>(z,   w3b, nullptr,
      nullptr, nullptr, nullptr, ssm, outp);
}